// Round 5
// baseline (194.898 us; speedup 1.0000x reference)
//
#include <hip/hip_runtime.h>

#define NB 64      // L*B batches
#define T 1024     // t1 == t2
#define HD 128     // h

// encoded +inf for order-preserving float-as-uint atomicMin
#define EINF 0xFF800000u

typedef __attribute__((ext_vector_type(8))) short bf16x8;
typedef __attribute__((ext_vector_type(4))) float f32x4;

static __device__ __forceinline__ short f2bf(float f) {
    unsigned u = __float_as_uint(f);
    u += 0x7FFFu + ((u >> 16) & 1u);
    return (short)(u >> 16);
}
static __device__ __forceinline__ unsigned fenc(float f) {
    unsigned b = __float_as_uint(f);
    return b ^ (unsigned)(((int)b >> 31) | (int)0x80000000);
}
static __device__ __forceinline__ float fdec(unsigned u) {
    unsigned m = (~(unsigned)((int)u >> 31)) | 0x80000000u;
    return __uint_as_float(u ^ m);
}

// Phase 0: y fp32 -> bf16; x,y per-row norms; all workspace init. Pure BW.
__global__ void wmd_prep(const float* __restrict__ x, const float* __restrict__ y,
                         short* __restrict__ ybf,
                         float* __restrict__ x2, float* __restrict__ y2,
                         unsigned* __restrict__ g_colmin, unsigned* __restrict__ g_rowmin,
                         float* __restrict__ sums, unsigned* __restrict__ batch_cnt,
                         unsigned* __restrict__ g_cnt) {
    int gi = blockIdx.x * 256 + threadIdx.x;          // float4 index, 2.097M total
    float4 vx = reinterpret_cast<const float4*>(x)[gi];
    float4 vy = reinterpret_cast<const float4*>(y)[gi];
    short4 sy;
    sy.x = f2bf(vy.x); sy.y = f2bf(vy.y); sy.z = f2bf(vy.z); sy.w = f2bf(vy.w);
    reinterpret_cast<short4*>(ybf)[gi] = sy;
    float px = vx.x * vx.x + vx.y * vx.y + vx.z * vx.z + vx.w * vx.w;
    float py = vy.x * vy.x + vy.y * vy.y + vy.z * vy.z + vy.w * vy.w;
    px += __shfl_xor(px, 1);  px += __shfl_xor(px, 2);  px += __shfl_xor(px, 4);
    px += __shfl_xor(px, 8);  px += __shfl_xor(px, 16);
    py += __shfl_xor(py, 1);  py += __shfl_xor(py, 2);  py += __shfl_xor(py, 4);
    py += __shfl_xor(py, 8);  py += __shfl_xor(py, 16);
    if ((threadIdx.x & 31) == 0) { x2[gi >> 5] = px; y2[gi >> 5] = py; }
    if (gi < NB * T) { g_colmin[gi] = EINF; g_rowmin[gi] = EINF; }
    if (gi < 2) sums[gi] = 0.f;
    if (gi < NB + 66 && gi >= 2) batch_cnt[gi - 2] = 0u;   // covers batch_cnt[64] + g_cnt
    if (gi == NB + 66) g_cnt[0] = 0u;
}

// Phase 1: fused bf16-MFMA GEMM + min tracking + per-batch reduce + finalize.
// 1024 blocks, 256 threads; per wave 32i x 64j. B tiles (64x128) DMA'd via
// global_load_lds (16B, XOR-swizzled), double-buffered. A converted from fp32.
__global__ __launch_bounds__(256, 4)
void wmd_main(const float* __restrict__ x, const short* __restrict__ ybf,
              const float* __restrict__ x2g, const float* __restrict__ y2g,
              unsigned* __restrict__ g_colmin, unsigned* __restrict__ g_rowmin,
              float* __restrict__ sums, unsigned* __restrict__ batch_cnt,
              unsigned* __restrict__ g_cnt, float* __restrict__ out) {
    __shared__ short b_sm[2][64 * 128];        // 2 x 16 KB
    __shared__ float y2_sm[512];
    __shared__ unsigned col_min_sm[512];
    __shared__ unsigned last_sm;
    __shared__ float red_sm[8];

    const int tid  = threadIdx.x;
    const int lin  = blockIdx.y * 16 + blockIdx.x;   // 0..1023
    const int m    = (lin >> 3) & 7;                 // i-tile 0..7
    const int grp  = ((lin >> 6) << 3) | (lin & 7);  // 0..127: (n, j-half) group
    const int n    = grp >> 1;
    const int i0   = m * 128;
    const int j0   = (grp & 1) * 512;
    const int lane = tid & 63;
    const int wave = tid >> 6;
    const int l16  = lane & 15, quad = lane >> 4;
    const float FINF = __uint_as_float(0x7F800000u);

    #pragma unroll
    for (int e = tid; e < 512; e += 256) col_min_sm[e] = EINF;

#define ISSUE_GLLS(pbuf, jtile)                                                   \
    {                                                                             \
        const short* ybase = ybf + (((size_t)(n * T + j0 + (jtile) * 64)) << 7);  \
        _Pragma("unroll")                                                         \
        for (int it = 0; it < 4; ++it) {                                          \
            int g   = wave * 4 + it;                                              \
            int s   = g * 64 + lane;                                              \
            int row = s >> 4;                                                     \
            int c   = (s & 15) ^ (row & 7);                                       \
            const short* gp = ybase + row * 128 + c * 8;                          \
            __builtin_amdgcn_global_load_lds(                                     \
                (const __attribute__((address_space(1))) void*)gp,                \
                (__attribute__((address_space(3))) void*)&b_sm[pbuf][g * 512],    \
                16, 0, 0);                                                        \
        }                                                                         \
    }

    ISSUE_GLLS(0, 0);   // tile-0 DMA overlaps prologue

    // ---- A fragments: fp32 x -> bf16 regs (norms come from prep) ----
    bf16x8 af[2][4];
    #pragma unroll
    for (int mi = 0; mi < 2; ++mi)
        #pragma unroll
        for (int kk = 0; kk < 4; ++kk) {
            const float4* gp = reinterpret_cast<const float4*>(
                x + (((size_t)(n * T + i0 + wave * 32 + mi * 16 + l16)) << 7) + kk * 32 + quad * 8);
            float4 a = gp[0], b = gp[1];
            bf16x8 f;
            f[0] = f2bf(a.x); f[1] = f2bf(a.y); f[2] = f2bf(a.z); f[3] = f2bf(a.w);
            f[4] = f2bf(b.x); f[5] = f2bf(b.y); f[6] = f2bf(b.z); f[7] = f2bf(b.w);
            af[mi][kk] = f;
        }
    float x2v[8];
    #pragma unroll
    for (int mi = 0; mi < 2; ++mi)
        #pragma unroll
        for (int r = 0; r < 4; ++r)
            x2v[mi * 4 + r] = x2g[n * T + i0 + wave * 32 + mi * 16 + quad * 4 + r];
    #pragma unroll
    for (int e = tid; e < 512; e += 256) y2_sm[e] = y2g[n * T + j0 + e];

    float rmin[8];
    #pragma unroll
    for (int q = 0; q < 8; ++q) rmin[q] = FINF;

    __syncthreads();    // y2_sm visible; tile-0 DMA drained

    for (int jt = 0; jt < 8; ++jt) {
        const int p = jt & 1;
        if (jt < 7) ISSUE_GLLS(p ^ 1, jt + 1);   // overlaps this iter's compute

        float y2v[4];
        #pragma unroll
        for (int ni = 0; ni < 4; ++ni)
            y2v[ni] = y2_sm[jt * 64 + ni * 16 + l16];

        f32x4 acc[2][4];
        #pragma unroll
        for (int mi = 0; mi < 2; ++mi)
            #pragma unroll
            for (int ni = 0; ni < 4; ++ni) {
                f32x4 z = {0.f, 0.f, 0.f, 0.f};
                acc[mi][ni] = z;
            }

        #pragma unroll
        for (int kk = 0; kk < 4; ++kk) {
            bf16x8 bv[4];
            #pragma unroll
            for (int ni = 0; ni < 4; ++ni) {
                int row = ni * 16 + l16;
                int c   = (kk * 4 + quad) ^ (row & 7);
                bv[ni] = *reinterpret_cast<const bf16x8*>(&b_sm[p][(row * 16 + c) * 8]);
            }
            #pragma unroll
            for (int mi = 0; mi < 2; ++mi)
                #pragma unroll
                for (int ni = 0; ni < 4; ++ni)
                    acc[mi][ni] = __builtin_amdgcn_mfma_f32_16x16x32_bf16(
                        af[mi][kk], bv[ni], acc[mi][ni], 0, 0, 0);
        }

        // ---- epilogue: fold mins (norm-add + clamp deferred) ----
        float vcol[4] = {FINF, FINF, FINF, FINF};
        #pragma unroll
        for (int mi = 0; mi < 2; ++mi)
            #pragma unroll
            for (int r = 0; r < 4; ++r) {
                float x2r = x2v[mi * 4 + r];
                #pragma unroll
                for (int ni = 0; ni < 4; ++ni) {
                    float xy = acc[mi][ni][r];
                    rmin[mi * 4 + r] = fminf(rmin[mi * 4 + r], fmaf(-2.f, xy, y2v[ni]));
                    vcol[ni]         = fminf(vcol[ni],         fmaf(-2.f, xy, x2r));
                }
            }
        #pragma unroll
        for (int ni = 0; ni < 4; ++ni) {
            float v = vcol[ni];
            v = fminf(v, __shfl_xor(v, 16));
            v = fminf(v, __shfl_xor(v, 32));
            if (lane < 16)
                atomicMin(&col_min_sm[jt * 64 + ni * 16 + lane], fenc(v));
        }
        __syncthreads();   // drains next-tile DMA; orders buffer reuse
    }

    // ---- flush mins to global (device-scope atomics) ----
    #pragma unroll
    for (int mi = 0; mi < 2; ++mi)
        #pragma unroll
        for (int r = 0; r < 4; ++r) {
            float v = rmin[mi * 4 + r];
            v = fminf(v, __shfl_xor(v, 1));
            v = fminf(v, __shfl_xor(v, 2));
            v = fminf(v, __shfl_xor(v, 4));
            v = fminf(v, __shfl_xor(v, 8));
            if (l16 == 0)
                atomicMin(&g_rowmin[n * T + i0 + wave * 32 + mi * 16 + quad * 4 + r], fenc(v));
        }
    #pragma unroll
    for (int e = tid; e < 512; e += 256)
        atomicMin(&g_colmin[n * T + j0 + e], col_min_sm[e]);

    // ---- per-batch completion; last of 16 blocks reduces batch n ----
    __threadfence();
    if (tid == 0) last_sm = atomicAdd(&batch_cnt[n], 1u);
    __syncthreads();
    if (last_sm != 15u) return;

    __threadfence();   // acquire side
    float sc = 0.f, sr = 0.f;
    for (int e = tid; e < T; e += 256) {
        unsigned cu = __hip_atomic_load(&g_colmin[n * T + e], __ATOMIC_RELAXED,
                                        __HIP_MEMORY_SCOPE_AGENT);
        unsigned ru = __hip_atomic_load(&g_rowmin[n * T + e], __ATOMIC_RELAXED,
                                        __HIP_MEMORY_SCOPE_AGENT);
        sc += sqrtf(fmaxf(fdec(cu) + y2g[n * T + e], 0.f));
        sr += sqrtf(fmaxf(fdec(ru) + x2g[n * T + e], 0.f));
    }
    #pragma unroll
    for (int o = 1; o < 64; o <<= 1) {
        sc += __shfl_xor(sc, o);
        sr += __shfl_xor(sr, o);
    }
    if (lane == 0) { red_sm[wave] = sc; red_sm[4 + wave] = sr; }
    __syncthreads();
    if (tid == 0) {
        atomicAdd(&sums[0], red_sm[0] + red_sm[1] + red_sm[2] + red_sm[3]);
        atomicAdd(&sums[1], red_sm[4] + red_sm[5] + red_sm[6] + red_sm[7]);
        __threadfence();
        unsigned old = atomicAdd(g_cnt, 1u);
        if (old == NB - 1) {
            float a = __hip_atomic_load(&sums[0], __ATOMIC_RELAXED, __HIP_MEMORY_SCOPE_AGENT);
            float b = __hip_atomic_load(&sums[1], __ATOMIC_RELAXED, __HIP_MEMORY_SCOPE_AGENT);
            out[0] = fmaxf(a, b) * (1.0f / 67108864.0f);
        }
    }
}

extern "C" void kernel_launch(void* const* d_in, const int* in_sizes, int n_in,
                              void* d_out, int out_size, void* d_ws, size_t ws_size,
                              hipStream_t stream) {
    const float* x = (const float*)d_in[0];
    const float* y = (const float*)d_in[1];
    float* out = (float*)d_out;

    char* ws = (char*)d_ws;
    unsigned* g_colmin  = (unsigned*)(ws);                    // 256 KB
    unsigned* g_rowmin  = (unsigned*)(ws + 256 * 1024);       // 256 KB
    float*    x2g       = (float*)(ws + 512 * 1024);          // 256 KB
    float*    y2g       = (float*)(ws + 768 * 1024);          // 256 KB
    float*    sums      = (float*)(ws + 1024 * 1024);         // 2 f32
    unsigned* batch_cnt = (unsigned*)(ws + 1024 * 1024 + 256);// 64 u32
    unsigned* g_cnt     = (unsigned*)(ws + 1024 * 1024 + 2048);// 1 u32
    short*    ybf       = (short*)(ws + 2 * 1024 * 1024);     // 16 MB

    wmd_prep<<<(NB * T * HD / 4) / 256, 256, 0, stream>>>(
        x, y, ybf, x2g, y2g, g_colmin, g_rowmin, sums, batch_cnt, g_cnt);
    wmd_main<<<dim3(16, NB), 256, 0, stream>>>(
        x, ybf, x2g, y2g, g_colmin, g_rowmin, sums, batch_cnt, g_cnt, out);
}

// Round 6
// 128.207 us; speedup vs baseline: 1.5202x; 1.5202x over previous
//
#include <hip/hip_runtime.h>

#define NB 64      // L*B batches
#define T 1024     // t1 == t2
#define HD 128     // h

// encoded +inf for order-preserving float-as-uint atomicMin
#define EINF 0xFF800000u

typedef __attribute__((ext_vector_type(8))) short bf16x8;
typedef __attribute__((ext_vector_type(4))) float f32x4;

static __device__ __forceinline__ short f2bf(float f) {
    unsigned u = __float_as_uint(f);
    u += 0x7FFFu + ((u >> 16) & 1u);
    return (short)(u >> 16);
}
static __device__ __forceinline__ unsigned fenc(float f) {
    unsigned b = __float_as_uint(f);
    return b ^ (unsigned)(((int)b >> 31) | (int)0x80000000);
}
static __device__ __forceinline__ float fdec(unsigned u) {
    unsigned m = (~(unsigned)((int)u >> 31)) | 0x80000000u;
    return __uint_as_float(u ^ m);
}

// Phase 0: x,y fp32 -> bf16 + per-row norms + all workspace init. Pure BW.
__global__ void wmd_prep(const float* __restrict__ x, const float* __restrict__ y,
                         short* __restrict__ xbf, short* __restrict__ ybf,
                         float* __restrict__ x2, float* __restrict__ y2,
                         unsigned* __restrict__ g_colmin, unsigned* __restrict__ g_rowmin,
                         float* __restrict__ sums, unsigned* __restrict__ batch_cnt,
                         unsigned* __restrict__ g_cnt) {
    int gi = blockIdx.x * 256 + threadIdx.x;          // float4 index, 2.097M total
    float4 vx = reinterpret_cast<const float4*>(x)[gi];
    float4 vy = reinterpret_cast<const float4*>(y)[gi];
    short4 sx, sy;
    sx.x = f2bf(vx.x); sx.y = f2bf(vx.y); sx.z = f2bf(vx.z); sx.w = f2bf(vx.w);
    sy.x = f2bf(vy.x); sy.y = f2bf(vy.y); sy.z = f2bf(vy.z); sy.w = f2bf(vy.w);
    reinterpret_cast<short4*>(xbf)[gi] = sx;
    reinterpret_cast<short4*>(ybf)[gi] = sy;
    float px = vx.x * vx.x + vx.y * vx.y + vx.z * vx.z + vx.w * vx.w;
    float py = vy.x * vy.x + vy.y * vy.y + vy.z * vy.z + vy.w * vy.w;
    px += __shfl_xor(px, 1);  px += __shfl_xor(px, 2);  px += __shfl_xor(px, 4);
    px += __shfl_xor(px, 8);  px += __shfl_xor(px, 16);
    py += __shfl_xor(py, 1);  py += __shfl_xor(py, 2);  py += __shfl_xor(py, 4);
    py += __shfl_xor(py, 8);  py += __shfl_xor(py, 16);
    if ((threadIdx.x & 31) == 0) { x2[gi >> 5] = px; y2[gi >> 5] = py; }
    if (gi < NB * T) { g_colmin[gi] = EINF; g_rowmin[gi] = EINF; }
    if (gi < 2) sums[gi] = 0.f;
    if (gi >= 4 && gi < 4 + NB) batch_cnt[gi - 4] = 0u;
    if (gi == 4 + NB) g_cnt[0] = 0u;
}

// Phase 1: fused bf16-MFMA GEMM + min tracking + fence-free per-batch reduce.
// 1024 blocks, 256 threads; per wave 32i x 64j. B tiles (64x128) DMA'd via
// global_load_lds (16B, XOR-swizzled), double-buffered. A frags direct from xbf.
// NO __threadfence anywhere: all shared data moves via device-scope atomics
// (coherent point); ordering via s_waitcnt vmcnt(0) only (no L2 invalidate).
__global__ __launch_bounds__(256, 4)
void wmd_main(const short* __restrict__ xbf, const short* __restrict__ ybf,
              const float* __restrict__ x2g, const float* __restrict__ y2g,
              unsigned* __restrict__ g_colmin, unsigned* __restrict__ g_rowmin,
              float* __restrict__ sums, unsigned* __restrict__ batch_cnt,
              unsigned* __restrict__ g_cnt, float* __restrict__ out) {
    __shared__ short b_sm[2][64 * 128];        // 2 x 16 KB
    __shared__ float y2_sm[512];
    __shared__ unsigned col_min_sm[512];
    __shared__ unsigned last_sm;
    __shared__ float red_sm[8];

    const int tid  = threadIdx.x;
    const int lin  = blockIdx.y * 16 + blockIdx.x;   // 0..1023
    const int m    = (lin >> 3) & 7;                 // i-tile 0..7
    const int grp  = ((lin >> 6) << 3) | (lin & 7);  // 0..127: (n, j-half) group
    const int n    = grp >> 1;
    const int i0   = m * 128;
    const int j0   = (grp & 1) * 512;
    const int lane = tid & 63;
    const int wave = tid >> 6;
    const int l16  = lane & 15, quad = lane >> 4;
    const float FINF = __uint_as_float(0x7F800000u);

    #pragma unroll
    for (int e = tid; e < 512; e += 256) col_min_sm[e] = EINF;

#define ISSUE_GLLS(pbuf, jtile)                                                   \
    {                                                                             \
        const short* ybase = ybf + (((size_t)(n * T + j0 + (jtile) * 64)) << 7);  \
        _Pragma("unroll")                                                         \
        for (int it = 0; it < 4; ++it) {                                          \
            int g   = wave * 4 + it;                                              \
            int s   = g * 64 + lane;                                              \
            int row = s >> 4;                                                     \
            int c   = (s & 15) ^ (row & 7);                                       \
            const short* gp = ybase + row * 128 + c * 8;                          \
            __builtin_amdgcn_global_load_lds(                                     \
                (const __attribute__((address_space(1))) void*)gp,                \
                (__attribute__((address_space(3))) void*)&b_sm[pbuf][g * 512],    \
                16, 0, 0);                                                        \
        }                                                                         \
    }

    ISSUE_GLLS(0, 0);   // tile-0 DMA overlaps prologue

    // ---- A fragments: straight bf16 global -> regs; norms from prep ----
    bf16x8 af[2][4];
    #pragma unroll
    for (int mi = 0; mi < 2; ++mi)
        #pragma unroll
        for (int kk = 0; kk < 4; ++kk)
            af[mi][kk] = *reinterpret_cast<const bf16x8*>(
                xbf + (((size_t)(n * T + i0 + wave * 32 + mi * 16 + l16)) << 7)
                    + kk * 32 + quad * 8);
    float x2v[8];
    #pragma unroll
    for (int mi = 0; mi < 2; ++mi)
        #pragma unroll
        for (int r = 0; r < 4; ++r)
            x2v[mi * 4 + r] = x2g[n * T + i0 + wave * 32 + mi * 16 + quad * 4 + r];
    #pragma unroll
    for (int e = tid; e < 512; e += 256) y2_sm[e] = y2g[n * T + j0 + e];

    float rmin[8];
    #pragma unroll
    for (int q = 0; q < 8; ++q) rmin[q] = FINF;

    __syncthreads();    // y2_sm visible; tile-0 DMA drained

    for (int jt = 0; jt < 8; ++jt) {
        const int p = jt & 1;
        if (jt < 7) ISSUE_GLLS(p ^ 1, jt + 1);   // overlaps this iter's compute

        float y2v[4];
        #pragma unroll
        for (int ni = 0; ni < 4; ++ni)
            y2v[ni] = y2_sm[jt * 64 + ni * 16 + l16];

        f32x4 acc[2][4];
        #pragma unroll
        for (int mi = 0; mi < 2; ++mi)
            #pragma unroll
            for (int ni = 0; ni < 4; ++ni) {
                f32x4 z = {0.f, 0.f, 0.f, 0.f};
                acc[mi][ni] = z;
            }

        #pragma unroll
        for (int kk = 0; kk < 4; ++kk) {
            bf16x8 bv[4];
            #pragma unroll
            for (int ni = 0; ni < 4; ++ni) {
                int row = ni * 16 + l16;
                int c   = (kk * 4 + quad) ^ (row & 7);
                bv[ni] = *reinterpret_cast<const bf16x8*>(&b_sm[p][(row * 16 + c) * 8]);
            }
            #pragma unroll
            for (int mi = 0; mi < 2; ++mi)
                #pragma unroll
                for (int ni = 0; ni < 4; ++ni)
                    acc[mi][ni] = __builtin_amdgcn_mfma_f32_16x16x32_bf16(
                        af[mi][kk], bv[ni], acc[mi][ni], 0, 0, 0);
        }

        // ---- epilogue: fold mins (norm-add + clamp deferred) ----
        float vcol[4] = {FINF, FINF, FINF, FINF};
        #pragma unroll
        for (int mi = 0; mi < 2; ++mi)
            #pragma unroll
            for (int r = 0; r < 4; ++r) {
                float x2r = x2v[mi * 4 + r];
                #pragma unroll
                for (int ni = 0; ni < 4; ++ni) {
                    float xy = acc[mi][ni][r];
                    rmin[mi * 4 + r] = fminf(rmin[mi * 4 + r], fmaf(-2.f, xy, y2v[ni]));
                    vcol[ni]         = fminf(vcol[ni],         fmaf(-2.f, xy, x2r));
                }
            }
        #pragma unroll
        for (int ni = 0; ni < 4; ++ni) {
            float v = vcol[ni];
            v = fminf(v, __shfl_xor(v, 16));
            v = fminf(v, __shfl_xor(v, 32));
            if (lane < 16)
                atomicMin(&col_min_sm[jt * 64 + ni * 16 + lane], fenc(v));
        }
        __syncthreads();   // drains next-tile DMA; orders buffer reuse
    }

    // ---- flush mins to global (device-scope atomics; coherent point) ----
    #pragma unroll
    for (int e = tid; e < 512; e += 256)
        atomicMin(&g_colmin[n * T + j0 + e], col_min_sm[e]);
    #pragma unroll
    for (int mi = 0; mi < 2; ++mi)
        #pragma unroll
        for (int r = 0; r < 4; ++r) {
            float v = rmin[mi * 4 + r];
            v = fminf(v, __shfl_xor(v, 1));
            v = fminf(v, __shfl_xor(v, 2));
            v = fminf(v, __shfl_xor(v, 4));
            v = fminf(v, __shfl_xor(v, 8));
            if (l16 == 0)
                atomicMin(&g_rowmin[n * T + i0 + wave * 32 + mi * 16 + quad * 4 + r], fenc(v));
        }

    // ---- fence-free completion protocol ----
    __builtin_amdgcn_s_waitcnt(0);   // this wave's atomics acked at coherent point
    __syncthreads();                 // all waves of block done
    if (tid == 0)
        last_sm = __hip_atomic_fetch_add(&batch_cnt[n], 1u, __ATOMIC_RELAXED,
                                         __HIP_MEMORY_SCOPE_AGENT);
    __syncthreads();
    if (last_sm != 15u) return;

    // last block of batch n: reduce its 1024 row/col mins
    float sc = 0.f, sr = 0.f;
    for (int e = tid; e < T; e += 256) {
        unsigned cu = __hip_atomic_load(&g_colmin[n * T + e], __ATOMIC_RELAXED,
                                        __HIP_MEMORY_SCOPE_AGENT);
        unsigned ru = __hip_atomic_load(&g_rowmin[n * T + e], __ATOMIC_RELAXED,
                                        __HIP_MEMORY_SCOPE_AGENT);
        sc += sqrtf(fmaxf(fdec(cu) + y2g[n * T + e], 0.f));
        sr += sqrtf(fmaxf(fdec(ru) + x2g[n * T + e], 0.f));
    }
    #pragma unroll
    for (int o = 1; o < 64; o <<= 1) {
        sc += __shfl_xor(sc, o);
        sr += __shfl_xor(sr, o);
    }
    if (lane == 0) { red_sm[wave] = sc; red_sm[4 + wave] = sr; }
    __syncthreads();
    if (tid == 0) {
        atomicAdd(&sums[0], red_sm[0] + red_sm[1] + red_sm[2] + red_sm[3]);
        atomicAdd(&sums[1], red_sm[4] + red_sm[5] + red_sm[6] + red_sm[7]);
        __builtin_amdgcn_s_waitcnt(0);   // sums adds acked before counter bump
        unsigned old = __hip_atomic_fetch_add(g_cnt, 1u, __ATOMIC_RELAXED,
                                              __HIP_MEMORY_SCOPE_AGENT);
        if (old == NB - 1) {
            float a = __hip_atomic_load(&sums[0], __ATOMIC_RELAXED, __HIP_MEMORY_SCOPE_AGENT);
            float b = __hip_atomic_load(&sums[1], __ATOMIC_RELAXED, __HIP_MEMORY_SCOPE_AGENT);
            out[0] = fmaxf(a, b) * (1.0f / 67108864.0f);
        }
    }
}

extern "C" void kernel_launch(void* const* d_in, const int* in_sizes, int n_in,
                              void* d_out, int out_size, void* d_ws, size_t ws_size,
                              hipStream_t stream) {
    const float* x = (const float*)d_in[0];
    const float* y = (const float*)d_in[1];
    float* out = (float*)d_out;

    char* ws = (char*)d_ws;
    unsigned* g_colmin  = (unsigned*)(ws);                     // 256 KB
    unsigned* g_rowmin  = (unsigned*)(ws + 256 * 1024);        // 256 KB
    float*    x2g       = (float*)(ws + 512 * 1024);           // 256 KB
    float*    y2g       = (float*)(ws + 768 * 1024);           // 256 KB
    float*    sums      = (float*)(ws + 1024 * 1024);          // 2 f32
    unsigned* batch_cnt = (unsigned*)(ws + 1024 * 1024 + 256); // 64 u32
    unsigned* g_cnt     = (unsigned*)(ws + 1024 * 1024 + 2048);// 1 u32
    short*    xbf       = (short*)(ws + 2 * 1024 * 1024);      // 16 MB
    short*    ybf       = (short*)(ws + 20 * 1024 * 1024);     // 16 MB

    wmd_prep<<<(NB * T * HD / 4) / 256, 256, 0, stream>>>(
        x, y, xbf, ybf, x2g, y2g, g_colmin, g_rowmin, sums, batch_cnt, g_cnt);
    wmd_main<<<dim3(16, NB), 256, 0, stream>>>(
        xbf, ybf, x2g, y2g, g_colmin, g_rowmin, sums, batch_cnt, g_cnt, out);
}

// Round 7
// 125.526 us; speedup vs baseline: 1.5527x; 1.0214x over previous
//
#include <hip/hip_runtime.h>

#define NB 64      // L*B batches
#define T 1024     // t1 == t2
#define HD 128     // h

// encoded +inf for order-preserving float-as-uint atomicMin
#define EINF 0xFF800000u

typedef __attribute__((ext_vector_type(8))) short bf16x8;
typedef __attribute__((ext_vector_type(4))) float f32x4;

static __device__ __forceinline__ short f2bf(float f) {
    unsigned u = __float_as_uint(f);
    u += 0x7FFFu + ((u >> 16) & 1u);
    return (short)(u >> 16);
}
static __device__ __forceinline__ unsigned fenc(float f) {
    unsigned b = __float_as_uint(f);
    return b ^ (unsigned)(((int)b >> 31) | (int)0x80000000);
}
static __device__ __forceinline__ float fdec(unsigned u) {
    unsigned m = (~(unsigned)((int)u >> 31)) | 0x80000000u;
    return __uint_as_float(u ^ m);
}

// Phase 0: y fp32 -> bf16 + y row norms + workspace init. ~51 MB, pure BW.
__global__ void wmd_prep(const float* __restrict__ y, short* __restrict__ ybf,
                         float* __restrict__ y2,
                         unsigned* __restrict__ g_colmin, unsigned* __restrict__ g_rowmin,
                         float* __restrict__ sums, unsigned* __restrict__ batch_cnt,
                         unsigned* __restrict__ g_cnt) {
    int gi = blockIdx.x * 256 + threadIdx.x;          // float4 index, 2.097M total
    float4 vy = reinterpret_cast<const float4*>(y)[gi];
    short4 sy;
    sy.x = f2bf(vy.x); sy.y = f2bf(vy.y); sy.z = f2bf(vy.z); sy.w = f2bf(vy.w);
    reinterpret_cast<short4*>(ybf)[gi] = sy;
    float py = vy.x * vy.x + vy.y * vy.y + vy.z * vy.z + vy.w * vy.w;
    py += __shfl_xor(py, 1);  py += __shfl_xor(py, 2);  py += __shfl_xor(py, 4);
    py += __shfl_xor(py, 8);  py += __shfl_xor(py, 16);
    if ((threadIdx.x & 31) == 0) y2[gi >> 5] = py;
    if (gi < NB * T) { g_colmin[gi] = EINF; g_rowmin[gi] = EINF; }
    if (gi < 2) sums[gi] = 0.f;
    if (gi >= 4 && gi < 4 + NB) batch_cnt[gi - 4] = 0u;
    if (gi == 4 + NB) g_cnt[0] = 0u;
}

// Phase 1: fused bf16-MFMA GEMM + min tracking + fence-free per-batch reduce.
// 1024 blocks, 256 threads; per wave 32i x 64j. B tiles (64x128) DMA'd via
// global_load_lds (16B, XOR-swizzled), double-buffered. A converted from fp32 x
// in the prologue (norms computed exactly in fp32 via quad shuffles).
// Norms are pre-added before the global min flush, so the reduce tail only
// touches the (atomically-written) min arrays. No __threadfence anywhere.
__global__ __launch_bounds__(256, 4)
void wmd_main(const float* __restrict__ x, const short* __restrict__ ybf,
              const float* __restrict__ y2g,
              unsigned* __restrict__ g_colmin, unsigned* __restrict__ g_rowmin,
              float* __restrict__ sums, unsigned* __restrict__ batch_cnt,
              unsigned* __restrict__ g_cnt, float* __restrict__ out) {
    __shared__ short b_sm[2][64 * 128];        // 2 x 16 KB
    __shared__ float y2_sm[512];
    __shared__ float x2_sm[128];
    __shared__ unsigned col_min_sm[512];
    __shared__ unsigned last_sm;
    __shared__ float red_sm[8];

    const int tid  = threadIdx.x;
    const int lin  = blockIdx.y * 16 + blockIdx.x;   // 0..1023
    const int m    = (lin >> 3) & 7;                 // i-tile 0..7
    const int grp  = ((lin >> 6) << 3) | (lin & 7);  // 0..127: (n, j-half) group
    const int n    = grp >> 1;
    const int i0   = m * 128;
    const int j0   = (grp & 1) * 512;
    const int lane = tid & 63;
    const int wave = tid >> 6;
    const int l16  = lane & 15, quad = lane >> 4;
    const float FINF = __uint_as_float(0x7F800000u);

    #pragma unroll
    for (int e = tid; e < 512; e += 256) col_min_sm[e] = EINF;

#define ISSUE_GLLS(pbuf, jtile)                                                   \
    {                                                                             \
        const short* ybase = ybf + (((size_t)(n * T + j0 + (jtile) * 64)) << 7);  \
        _Pragma("unroll")                                                         \
        for (int it = 0; it < 4; ++it) {                                          \
            int g   = wave * 4 + it;                                              \
            int s   = g * 64 + lane;                                              \
            int row = s >> 4;                                                     \
            int c   = (s & 15) ^ (row & 7);                                       \
            const short* gp = ybase + row * 128 + c * 8;                          \
            __builtin_amdgcn_global_load_lds(                                     \
                (const __attribute__((address_space(1))) void*)gp,                \
                (__attribute__((address_space(3))) void*)&b_sm[pbuf][g * 512],    \
                16, 0, 0);                                                        \
        }                                                                         \
    }

    ISSUE_GLLS(0, 0);   // tile-0 DMA overlaps prologue

    // ---- A fragments: fp32 x -> bf16 regs + exact fp32 row norms ----
    bf16x8 af[2][4];
    #pragma unroll
    for (int mi = 0; mi < 2; ++mi) {
        float part = 0.f;
        #pragma unroll
        for (int kk = 0; kk < 4; ++kk) {
            const float4* gp = reinterpret_cast<const float4*>(
                x + (((size_t)(n * T + i0 + wave * 32 + mi * 16 + l16)) << 7) + kk * 32 + quad * 8);
            float4 a = gp[0], b = gp[1];
            bf16x8 f;
            f[0] = f2bf(a.x); f[1] = f2bf(a.y); f[2] = f2bf(a.z); f[3] = f2bf(a.w);
            f[4] = f2bf(b.x); f[5] = f2bf(b.y); f[6] = f2bf(b.z); f[7] = f2bf(b.w);
            af[mi][kk] = f;
            part += a.x * a.x + a.y * a.y + a.z * a.z + a.w * a.w;
            part += b.x * b.x + b.y * b.y + b.z * b.z + b.w * b.w;
        }
        part += __shfl_xor(part, 16);
        part += __shfl_xor(part, 32);
        if (quad == 0) x2_sm[wave * 32 + mi * 16 + l16] = part;
    }
    #pragma unroll
    for (int e = tid; e < 512; e += 256) y2_sm[e] = y2g[n * T + j0 + e];

    float rmin[8];
    #pragma unroll
    for (int q = 0; q < 8; ++q) rmin[q] = FINF;

    __syncthreads();    // x2_sm/y2_sm visible; tile-0 DMA drained

    float x2v[8];
    #pragma unroll
    for (int mi = 0; mi < 2; ++mi)
        #pragma unroll
        for (int r = 0; r < 4; ++r)
            x2v[mi * 4 + r] = x2_sm[wave * 32 + mi * 16 + quad * 4 + r];

    for (int jt = 0; jt < 8; ++jt) {
        const int p = jt & 1;
        if (jt < 7) ISSUE_GLLS(p ^ 1, jt + 1);   // overlaps this iter's compute

        float y2v[4];
        #pragma unroll
        for (int ni = 0; ni < 4; ++ni)
            y2v[ni] = y2_sm[jt * 64 + ni * 16 + l16];

        f32x4 acc[2][4];
        #pragma unroll
        for (int mi = 0; mi < 2; ++mi)
            #pragma unroll
            for (int ni = 0; ni < 4; ++ni) {
                f32x4 z = {0.f, 0.f, 0.f, 0.f};
                acc[mi][ni] = z;
            }

        #pragma unroll
        for (int kk = 0; kk < 4; ++kk) {
            bf16x8 bv[4];
            #pragma unroll
            for (int ni = 0; ni < 4; ++ni) {
                int row = ni * 16 + l16;
                int c   = (kk * 4 + quad) ^ (row & 7);
                bv[ni] = *reinterpret_cast<const bf16x8*>(&b_sm[p][(row * 16 + c) * 8]);
            }
            #pragma unroll
            for (int mi = 0; mi < 2; ++mi)
                #pragma unroll
                for (int ni = 0; ni < 4; ++ni)
                    acc[mi][ni] = __builtin_amdgcn_mfma_f32_16x16x32_bf16(
                        af[mi][kk], bv[ni], acc[mi][ni], 0, 0, 0);
        }

        // ---- epilogue: fold mins (norm-add deferred to flush) ----
        float vcol[4] = {FINF, FINF, FINF, FINF};
        #pragma unroll
        for (int mi = 0; mi < 2; ++mi)
            #pragma unroll
            for (int r = 0; r < 4; ++r) {
                float x2r = x2v[mi * 4 + r];
                #pragma unroll
                for (int ni = 0; ni < 4; ++ni) {
                    float xy = acc[mi][ni][r];
                    rmin[mi * 4 + r] = fminf(rmin[mi * 4 + r], fmaf(-2.f, xy, y2v[ni]));
                    vcol[ni]         = fminf(vcol[ni],         fmaf(-2.f, xy, x2r));
                }
            }
        #pragma unroll
        for (int ni = 0; ni < 4; ++ni) {
            float v = vcol[ni];
            v = fminf(v, __shfl_xor(v, 16));
            v = fminf(v, __shfl_xor(v, 32));
            if (lane < 16)
                atomicMin(&col_min_sm[jt * 64 + ni * 16 + lane], fenc(v));
        }
        __syncthreads();   // drains next-tile DMA; orders buffer reuse
    }

    // ---- flush mins to global with norms pre-added (device-scope atomics) ----
    #pragma unroll
    for (int e = tid; e < 512; e += 256) {
        float v = fdec(col_min_sm[e]) + y2_sm[e];       // + y2_j for col e
        atomicMin(&g_colmin[n * T + j0 + e], fenc(v));
    }
    #pragma unroll
    for (int mi = 0; mi < 2; ++mi)
        #pragma unroll
        for (int r = 0; r < 4; ++r) {
            float v = rmin[mi * 4 + r] + x2v[mi * 4 + r];   // + x2_i for this row
            v = fminf(v, __shfl_xor(v, 1));
            v = fminf(v, __shfl_xor(v, 2));
            v = fminf(v, __shfl_xor(v, 4));
            v = fminf(v, __shfl_xor(v, 8));
            if (l16 == 0)
                atomicMin(&g_rowmin[n * T + i0 + wave * 32 + mi * 16 + quad * 4 + r], fenc(v));
        }

    // ---- fence-free completion protocol ----
    __builtin_amdgcn_s_waitcnt(0);   // this wave's atomics acked at coherent point
    __syncthreads();                 // all waves of block done
    if (tid == 0)
        last_sm = __hip_atomic_fetch_add(&batch_cnt[n], 1u, __ATOMIC_RELAXED,
                                         __HIP_MEMORY_SCOPE_AGENT);
    __syncthreads();
    if (last_sm != 15u) return;

    // last block of batch n: reduce its 1024 row/col mins (already full d^2)
    float sc = 0.f, sr = 0.f;
    for (int e = tid; e < T; e += 256) {
        unsigned cu = __hip_atomic_load(&g_colmin[n * T + e], __ATOMIC_RELAXED,
                                        __HIP_MEMORY_SCOPE_AGENT);
        unsigned ru = __hip_atomic_load(&g_rowmin[n * T + e], __ATOMIC_RELAXED,
                                        __HIP_MEMORY_SCOPE_AGENT);
        sc += sqrtf(fmaxf(fdec(cu), 0.f));
        sr += sqrtf(fmaxf(fdec(ru), 0.f));
    }
    #pragma unroll
    for (int o = 1; o < 64; o <<= 1) {
        sc += __shfl_xor(sc, o);
        sr += __shfl_xor(sr, o);
    }
    if (lane == 0) { red_sm[wave] = sc; red_sm[4 + wave] = sr; }
    __syncthreads();
    if (tid == 0) {
        atomicAdd(&sums[0], red_sm[0] + red_sm[1] + red_sm[2] + red_sm[3]);
        atomicAdd(&sums[1], red_sm[4] + red_sm[5] + red_sm[6] + red_sm[7]);
        __builtin_amdgcn_s_waitcnt(0);   // sums adds acked before counter bump
        unsigned old = __hip_atomic_fetch_add(g_cnt, 1u, __ATOMIC_RELAXED,
                                              __HIP_MEMORY_SCOPE_AGENT);
        if (old == NB - 1) {
            float a = __hip_atomic_load(&sums[0], __ATOMIC_RELAXED, __HIP_MEMORY_SCOPE_AGENT);
            float b = __hip_atomic_load(&sums[1], __ATOMIC_RELAXED, __HIP_MEMORY_SCOPE_AGENT);
            out[0] = fmaxf(a, b) * (1.0f / 67108864.0f);
        }
    }
}

extern "C" void kernel_launch(void* const* d_in, const int* in_sizes, int n_in,
                              void* d_out, int out_size, void* d_ws, size_t ws_size,
                              hipStream_t stream) {
    const float* x = (const float*)d_in[0];
    const float* y = (const float*)d_in[1];
    float* out = (float*)d_out;

    char* ws = (char*)d_ws;
    unsigned* g_colmin  = (unsigned*)(ws);                     // 256 KB
    unsigned* g_rowmin  = (unsigned*)(ws + 256 * 1024);        // 256 KB
    float*    y2g       = (float*)(ws + 512 * 1024);           // 256 KB
    float*    sums      = (float*)(ws + 768 * 1024);           // 2 f32
    unsigned* batch_cnt = (unsigned*)(ws + 768 * 1024 + 256);  // 64 u32
    unsigned* g_cnt     = (unsigned*)(ws + 768 * 1024 + 2048); // 1 u32
    short*    ybf       = (short*)(ws + 1024 * 1024);          // 16 MB

    wmd_prep<<<(NB * T * HD / 4) / 256, 256, 0, stream>>>(
        y, ybf, y2g, g_colmin, g_rowmin, sums, batch_cnt, g_cnt);
    wmd_main<<<dim3(16, NB), 256, 0, stream>>>(
        x, ybf, y2g, g_colmin, g_rowmin, sums, batch_cnt, g_cnt, out);
}